// Round 13
// baseline (122.111 us; speedup 1.0000x reference)
//
#include <hip/hip_runtime.h>

#define Bn 32
#define Tn 24
#define Dn 32
#define Hn 32
#define Cn 1024
#define DC (Dn*Cn)      /* 32768 */
#define TDC (Tn*Dn*Cn)  /* 786432 */
#define MP 34
#define PPXN (MP*MP)    /* 1156 */
#define IMGS (MP*MP*32) /* shorts per image (4 planes * 1156 * 8) */
#define SCALE 1.442695041f

typedef __attribute__((ext_vector_type(8))) short bf16x8;
typedef __attribute__((ext_vector_type(4))) float f32x4;

__device__ __forceinline__ unsigned cvt_pk(float lo, float hi) {
    unsigned r; asm("v_cvt_pk_bf16_f32 %0, %1, %2" : "=v"(r) : "v"(lo), "v"(hi)); return r;
}
__device__ __forceinline__ float lo16f(unsigned u) { return __builtin_bit_cast(float, u << 16); }
__device__ __forceinline__ float hi16f(unsigned u) { return __builtin_bit_cast(float, u & 0xffff0000u); }
__device__ __forceinline__ float rcp_(float x) { return __builtin_amdgcn_rcpf(x); }
__device__ __forceinline__ float exp2_(float x) { return __builtin_amdgcn_exp2f(x); }
__device__ __forceinline__ bf16x8 bc(int4 v) { return __builtin_bit_cast(bf16x8, v); }

struct __align__(16) LdsT {
    unsigned short Xh[2][2][16][48];  // [buf][cell][b][d pad48] hi plane
    unsigned short Xl[2][2][16][48];  // lo plane
    float Hf[2][2][16][36];           // [buf][cell][b][hid pad36] fp32 h
};  // 21504 B

// ---- zero the 1-px halo ring of every (img, chunk) plane ----
__global__ __launch_bounds__(512)
void zero_halo(unsigned short* __restrict__ sp) {
    int gid = blockIdx.x * 512 + threadIdx.x;
    if (gid >= 3072 * 132) return;
    int plane = gid / 132;
    int r = gid - plane * 132;
    int m, n;
    if (r < 34)       { m = 0;      n = r; }
    else if (r < 68)  { m = 33;     n = r - 34; }
    else if (r < 100) { m = r - 67; n = 0; }
    else              { m = r - 99; n = 33; }
    int4 z = {0, 0, 0, 0};
    *(int4*)(sp + ((size_t)plane * PPXN + m * MP + n) * 8) = z;
}

// ---- LSTM: grid 1024 = 512 cellpairs x 2 bslices; 256 thr = 4 waves ----
// wave w: cell ci = w>>1, gate-half gh = w&1. Block: 2 cells x 16 batch. M=16 tile.
// k11 structure + k10's allocator fix: waves_per_eu(4,4) stops the VGPR-halving
// heuristic that made k11 spill W to scratch (VGPR 64). Target: 4 blocks/CU.
__global__ __launch_bounds__(256) __attribute__((amdgpu_waves_per_eu(4, 4)))
void lstm_k13(const float* __restrict__ x,
              const float* __restrict__ Wih,
              const float* __restrict__ Whh,
              const float* __restrict__ bih,
              const float* __restrict__ bhh,
              unsigned short* __restrict__ sp)
{
    __shared__ LdsT lds;
    const int tid  = threadIdx.x;
    const int lane = tid & 63;
    const int wave = tid >> 6;
    const int ci   = wave >> 1;
    const int gh   = wave & 1;
    const int l16  = lane & 15;
    const int kg   = lane >> 4;
    const int bid  = blockIdx.x;
    const int xcd  = bid & 7, v = bid >> 3;        // v 0..127
    const int cg   = xcd * 64 + (v & 63);           // 0..511, XCD-contiguous cellpairs
    const int bs   = v >> 6;                        // 0..1
    const int cellbase = cg * 2;
    const int cell = cellbase + ci;
    const int gb0  = bs * 16;

    // ---- W fragments (int4), split hi/lo via cvt_pk, pre-scaled by log2e ----
    int4 wihh[4], wihl[4], whhh[4], whhl[4];
    float biasr[4];
#pragma unroll
    for (int q = 0; q < 4; ++q) {
        const int g = q * 32 + gh * 16 + l16;
        const float* wp = Wih + (size_t)cell * 4096 + g * 32 + kg * 8;
        const float* hp = Whh + (size_t)cell * 4096 + g * 32 + kg * 8;
        float wv[8], hv[8];
#pragma unroll
        for (int j = 0; j < 8; ++j) { wv[j] = wp[j] * SCALE; hv[j] = hp[j] * SCALE; }
        unsigned a0 = cvt_pk(wv[0], wv[1]), a1 = cvt_pk(wv[2], wv[3]);
        unsigned a2 = cvt_pk(wv[4], wv[5]), a3 = cvt_pk(wv[6], wv[7]);
        wihh[q] = int4{(int)a0, (int)a1, (int)a2, (int)a3};
        wihl[q] = int4{(int)cvt_pk(wv[0] - lo16f(a0), wv[1] - hi16f(a0)),
                       (int)cvt_pk(wv[2] - lo16f(a1), wv[3] - hi16f(a1)),
                       (int)cvt_pk(wv[4] - lo16f(a2), wv[5] - hi16f(a2)),
                       (int)cvt_pk(wv[6] - lo16f(a3), wv[7] - hi16f(a3))};
        unsigned b0 = cvt_pk(hv[0], hv[1]), b1 = cvt_pk(hv[2], hv[3]);
        unsigned b2 = cvt_pk(hv[4], hv[5]), b3 = cvt_pk(hv[6], hv[7]);
        whhh[q] = int4{(int)b0, (int)b1, (int)b2, (int)b3};
        whhl[q] = int4{(int)cvt_pk(hv[0] - lo16f(b0), hv[1] - hi16f(b0)),
                       (int)cvt_pk(hv[2] - lo16f(b1), hv[3] - hi16f(b1)),
                       (int)cvt_pk(hv[4] - lo16f(b2), hv[5] - hi16f(b2)),
                       (int)cvt_pk(hv[6] - lo16f(b3), hv[7] - hi16f(b3))};
        biasr[q] = (bih[cell * 128 + g] + bhh[cell * 128 + g]) * SCALE;
    }

    // ---- staging map: thread -> (b = tid>>4, d0 = (tid&15)*2), 2 float2 loads ----
    const int sb = tid >> 4;
    const int d0 = (tid & 15) * 2;
    const float* xg0 = x + (size_t)(gb0 + sb) * TDC + (size_t)d0 * Cn + cellbase;

    // ---- sp store map (gh==0 waves): lane -> (b_loc = lane&15, kg2 = lane>>4) ----
    const int b_loc = lane & 15, kg2 = lane >> 4;
    const int sm = cell >> 5, sn = cell & 31;
    const int ppx = (sm + 1) * MP + (sn + 1);
    unsigned short* spb = sp + (((size_t)(gb0 + b_loc) * (Tn * 4) + kg2) * PPXN + ppx) * 8;

    float hD[4] = {}, cst[4] = {};
    float2 nx0 = *(const float2*)xg0;
    float2 nx1 = *(const float2*)(xg0 + Cn);

    for (int t = 0; t < Tn; ++t) {
        const int bufi = t & 1;
        // -- stage x(t): split hi/lo, b32 writes --
#pragma unroll
        for (int cc = 0; cc < 2; ++cc) {
            float f0 = cc ? nx0.y : nx0.x;
            float f1 = cc ? nx1.y : nx1.x;
            unsigned a0 = cvt_pk(f0, f1);
            unsigned l0 = cvt_pk(f0 - lo16f(a0), f1 - hi16f(a0));
            *(unsigned*)&lds.Xh[bufi][cc][sb][d0] = a0;
            *(unsigned*)&lds.Xl[bufi][cc][sb][d0] = l0;
        }
        // -- write h(t-1) -> Hf[bufi] (rows kg*4+r, col gh*16+l16) --
#pragma unroll
        for (int r = 0; r < 4; ++r)
            lds.Hf[bufi][ci][kg * 4 + r][gh * 16 + l16] = hD[r];
        // -- prefetch x(t+1) --
        if (t < Tn - 1) {
            nx0 = *(const float2*)(xg0 + (size_t)(t + 1) * DC);
            nx1 = *(const float2*)(xg0 + (size_t)(t + 1) * DC + Cn);
        }
        __syncthreads();

        // -- fragments (rows b = l16, k = kg*8..+7) --
        int4 xfh = *(const int4*)&lds.Xh[bufi][ci][l16][kg * 8];
        int4 xfl = *(const int4*)&lds.Xl[bufi][ci][l16][kg * 8];
        const float* hp = &lds.Hf[bufi][ci][l16][kg * 8];
        float4 ha = *(const float4*)hp;
        float4 hb = *(const float4*)(hp + 4);
        unsigned p0 = cvt_pk(ha.x, ha.y), p1 = cvt_pk(ha.z, ha.w);
        unsigned p2 = cvt_pk(hb.x, hb.y), p3 = cvt_pk(hb.z, hb.w);
        int4 hfh = int4{(int)p0, (int)p1, (int)p2, (int)p3};
        int4 hfl = int4{(int)cvt_pk(ha.x - lo16f(p0), ha.y - hi16f(p0)),
                        (int)cvt_pk(ha.z - lo16f(p1), ha.w - hi16f(p1)),
                        (int)cvt_pk(hb.x - lo16f(p2), hb.y - hi16f(p2)),
                        (int)cvt_pk(hb.z - lo16f(p3), hb.w - hi16f(p3))};

        // -- sp store h(t-1) bf16-hi (gh==0 waves; (b_loc,kg2) == (l16,kg) map) --
        if (gh == 0 && t > 0) {
            int4 sv = {(int)p0, (int)p1, (int)p2, (int)p3};
            *(int4*)(spb + (size_t)(t - 1) * IMGS) = sv;
        }

        // -- MFMA: 4 q-tiles x 6-term split --
        f32x4 acc[4];
#pragma unroll
        for (int q = 0; q < 4; ++q) {
            f32x4 a = {biasr[q], biasr[q], biasr[q], biasr[q]};
            a = __builtin_amdgcn_mfma_f32_16x16x32_bf16(bc(xfh), bc(wihh[q]), a, 0, 0, 0);
            a = __builtin_amdgcn_mfma_f32_16x16x32_bf16(bc(xfl), bc(wihh[q]), a, 0, 0, 0);
            a = __builtin_amdgcn_mfma_f32_16x16x32_bf16(bc(xfh), bc(wihl[q]), a, 0, 0, 0);
            a = __builtin_amdgcn_mfma_f32_16x16x32_bf16(bc(hfh), bc(whhh[q]), a, 0, 0, 0);
            a = __builtin_amdgcn_mfma_f32_16x16x32_bf16(bc(hfl), bc(whhh[q]), a, 0, 0, 0);
            a = __builtin_amdgcn_mfma_f32_16x16x32_bf16(bc(hfh), bc(whhl[q]), a, 0, 0, 0);
            acc[q] = a;
        }

        // -- gates (pre-scaled by log2e): rows b = kg*4+r, h col gh*16+l16 --
#pragma unroll
        for (int r = 0; r < 4; ++r) {
            float gi = acc[0][r], gf = acc[1][r];
            float gg = acc[2][r], go = acc[3][r];
            float ig = rcp_(1.f + exp2_(-gi));
            float fg = rcp_(1.f + exp2_(-gf));
            float gt = 1.f - 2.f * rcp_(1.f + exp2_(gg + gg));
            float og = rcp_(1.f + exp2_(-go));
            float c  = fg * cst[r] + ig * gt;
            cst[r] = c;
            float tc = 1.f - 2.f * rcp_(1.f + exp2_((2.f * SCALE) * c));
            hD[r] = og * tc;
        }
    }

    // ---- epilogue: flush h(Tn-1) ----
#pragma unroll
    for (int r = 0; r < 4; ++r)
        lds.Hf[0][ci][kg * 4 + r][gh * 16 + l16] = hD[r];
    __syncthreads();
    if (gh == 0) {
        const float* hq = &lds.Hf[0][ci][l16][kg * 8];
        float4 ea = *(const float4*)hq;
        float4 eb = *(const float4*)(hq + 4);
        int4 sv = {(int)cvt_pk(ea.x, ea.y), (int)cvt_pk(ea.z, ea.w),
                   (int)cvt_pk(eb.x, eb.y), (int)cvt_pk(eb.z, eb.w)};
        *(int4*)(spb + (size_t)(Tn - 1) * IMGS) = sv;
    }
}

// ---- conv: 768 blocks (b,t) x 512 thr, 2 px/thread, fp32 math, fused sigmoid ----
__global__ __launch_bounds__(512, 4)
void conv_k4(const unsigned short* __restrict__ sp,
             const float* __restrict__ cw,
             const float* __restrict__ cb,
             float* __restrict__ out)
{
    __shared__ float wlds[9][32];
    const int tid = threadIdx.x;
    const int img = blockIdx.x;
    if (tid < 288) wlds[tid >> 5][tid & 31] = cw[(tid & 31) * 9 + (tid >> 5)];
    __syncthreads();
    const float bias = cb[0];
    float acc[2] = {bias, bias};
    int ppx[2];
#pragma unroll
    for (int pk = 0; pk < 2; ++pk) {
        int px = tid + pk * 512;
        ppx[pk] = ((px >> 5) + 1) * MP + (px & 31) + 1;
    }
#pragma unroll
    for (int hc = 0; hc < 4; ++hc) {
        float4 wa[9], wb[9];
#pragma unroll
        for (int tap = 0; tap < 9; ++tap) {
            wa[tap] = *(const float4*)&wlds[tap][hc * 8];
            wb[tap] = *(const float4*)&wlds[tap][hc * 8 + 4];
        }
        const unsigned short* plane = sp + (size_t)(img * 4 + hc) * (PPXN * 8);
#pragma unroll
        for (int pk = 0; pk < 2; ++pk) {
            const unsigned short* base = plane + (size_t)ppx[pk] * 8;
            float a = acc[pk];
#pragma unroll
            for (int dm = -1; dm <= 1; ++dm)
#pragma unroll
                for (int dn = -1; dn <= 1; ++dn) {
                    const int tap = (dm + 1) * 3 + (dn + 1);
                    int4 v = *(const int4*)(base + (dm * MP + dn) * 8);
                    float4 w0 = wa[tap], w1 = wb[tap];
                    a = fmaf(lo16f((unsigned)v.x), w0.x, a);
                    a = fmaf(hi16f((unsigned)v.x), w0.y, a);
                    a = fmaf(lo16f((unsigned)v.y), w0.z, a);
                    a = fmaf(hi16f((unsigned)v.y), w0.w, a);
                    a = fmaf(lo16f((unsigned)v.z), w1.x, a);
                    a = fmaf(hi16f((unsigned)v.z), w1.y, a);
                    a = fmaf(lo16f((unsigned)v.w), w1.z, a);
                    a = fmaf(hi16f((unsigned)v.w), w1.w, a);
                }
            acc[pk] = a;
        }
    }
#pragma unroll
    for (int pk = 0; pk < 2; ++pk)
        out[(size_t)img * 1024 + tid + pk * 512] = rcp_(1.f + exp2_(-SCALE * acc[pk]));
}

extern "C" void kernel_launch(void* const* d_in, const int* in_sizes, int n_in,
                              void* d_out, int out_size, void* d_ws, size_t ws_size,
                              hipStream_t stream) {
    const float* x   = (const float*)d_in[0];
    const float* Wih = (const float*)d_in[1];
    const float* Whh = (const float*)d_in[2];
    const float* bih = (const float*)d_in[3];
    const float* bhh = (const float*)d_in[4];
    const float* cw  = (const float*)d_in[5];
    const float* cb  = (const float*)d_in[6];
    float* out = (float*)d_out;
    unsigned short* sp = (unsigned short*)d_ws;  // bf16 (B,T, chunk4, 34,34, 8ch)

    zero_halo<<<792, 512, 0, stream>>>(sp);
    lstm_k13<<<1024, 256, 0, stream>>>(x, Wih, Whh, bih, bhh, sp);
    conv_k4<<<Bn * Tn, 512, 0, stream>>>(sp, cw, cb, out);
}

// Round 14
// 111.457 us; speedup vs baseline: 1.0956x; 1.0956x over previous
//
#include <hip/hip_runtime.h>

#define Bn 32
#define Tn 24
#define Dn 32
#define Hn 32
#define Cn 1024
#define DC (Dn*Cn)      /* 32768 */
#define TDC (Tn*Dn*Cn)  /* 786432 */
#define MP 34
#define PPXN (MP*MP)    /* 1156 */
#define IMGS (MP*MP*32) /* shorts per image (4 planes * 1156 * 8) */
#define SCALE 1.442695041f

typedef __attribute__((ext_vector_type(8))) short bf16x8;
typedef __attribute__((ext_vector_type(4))) float f32x4;

__device__ __forceinline__ unsigned cvt_pk(float lo, float hi) {
    unsigned r; asm("v_cvt_pk_bf16_f32 %0, %1, %2" : "=v"(r) : "v"(lo), "v"(hi)); return r;
}
__device__ __forceinline__ float lo16f(unsigned u) { return __builtin_bit_cast(float, u << 16); }
__device__ __forceinline__ float hi16f(unsigned u) { return __builtin_bit_cast(float, u & 0xffff0000u); }
__device__ __forceinline__ float rcp_(float x) { return __builtin_amdgcn_rcpf(x); }
__device__ __forceinline__ float exp2_(float x) { return __builtin_amdgcn_exp2f(x); }
__device__ __forceinline__ bf16x8 bc(int4 v) { return __builtin_bit_cast(bf16x8, v); }

struct __align__(16) LdsT {
    unsigned short Xh[2][2][16][48];  // [buf][cell][b][d pad48] bf16(x) only
    float Hf[2][2][16][36];           // [buf][cell][b][hid pad36] fp32 h
};  // 15360 B

// ---- zero the 1-px halo ring of every (img, chunk) plane ----
__global__ __launch_bounds__(512)
void zero_halo(unsigned short* __restrict__ sp) {
    int gid = blockIdx.x * 512 + threadIdx.x;
    if (gid >= 3072 * 132) return;
    int plane = gid / 132;
    int r = gid - plane * 132;
    int m, n;
    if (r < 34)       { m = 0;      n = r; }
    else if (r < 68)  { m = 33;     n = r - 34; }
    else if (r < 100) { m = r - 67; n = 0; }
    else              { m = r - 99; n = 33; }
    int4 z = {0, 0, 0, 0};
    *(int4*)(sp + ((size_t)plane * PPXN + m * MP + n) * 8) = z;
}

// ---- LSTM: grid 1024 = 512 cellpairs x 2 bslices; 256 thr = 4 waves ----
// wave w: cell ci = w>>1, gate-half gh = w&1. Block: 2 cells x 16 batch.
// waves_per_eu(3,3): the only proven spill-free allocation (k10: VGPR 80).
// Residency is resource-determined: 80 VGPR + 15KB LDS -> 4 blocks/CU fit.
// x-path is 2-term (bf16(x) * split-W): xl*Wh term dropped (error ~1e-3).
__global__ __launch_bounds__(256) __attribute__((amdgpu_waves_per_eu(3, 3)))
void lstm_k14(const float* __restrict__ x,
              const float* __restrict__ Wih,
              const float* __restrict__ Whh,
              const float* __restrict__ bih,
              const float* __restrict__ bhh,
              unsigned short* __restrict__ sp)
{
    __shared__ LdsT lds;
    const int tid  = threadIdx.x;
    const int lane = tid & 63;
    const int wave = tid >> 6;
    const int ci   = wave >> 1;
    const int gh   = wave & 1;
    const int l16  = lane & 15;
    const int kg   = lane >> 4;
    const int bid  = blockIdx.x;
    const int xcd  = bid & 7, v = bid >> 3;        // v 0..127
    const int cg   = xcd * 64 + (v & 63);           // 0..511, XCD-contiguous cellpairs
    const int bs   = v >> 6;                        // 0..1
    const int cellbase = cg * 2;
    const int cell = cellbase + ci;
    const int gb0  = bs * 16;

    // ---- W fragments (int4), split hi/lo via cvt_pk, pre-scaled by log2e ----
    int4 wihh[4], wihl[4], whhh[4], whhl[4];
    float biasr[4];
#pragma unroll
    for (int q = 0; q < 4; ++q) {
        const int g = q * 32 + gh * 16 + l16;
        const float* wp = Wih + (size_t)cell * 4096 + g * 32 + kg * 8;
        const float* hp = Whh + (size_t)cell * 4096 + g * 32 + kg * 8;
        float wv[8], hv[8];
#pragma unroll
        for (int j = 0; j < 8; ++j) { wv[j] = wp[j] * SCALE; hv[j] = hp[j] * SCALE; }
        unsigned a0 = cvt_pk(wv[0], wv[1]), a1 = cvt_pk(wv[2], wv[3]);
        unsigned a2 = cvt_pk(wv[4], wv[5]), a3 = cvt_pk(wv[6], wv[7]);
        wihh[q] = int4{(int)a0, (int)a1, (int)a2, (int)a3};
        wihl[q] = int4{(int)cvt_pk(wv[0] - lo16f(a0), wv[1] - hi16f(a0)),
                       (int)cvt_pk(wv[2] - lo16f(a1), wv[3] - hi16f(a1)),
                       (int)cvt_pk(wv[4] - lo16f(a2), wv[5] - hi16f(a2)),
                       (int)cvt_pk(wv[6] - lo16f(a3), wv[7] - hi16f(a3))};
        unsigned b0 = cvt_pk(hv[0], hv[1]), b1 = cvt_pk(hv[2], hv[3]);
        unsigned b2 = cvt_pk(hv[4], hv[5]), b3 = cvt_pk(hv[6], hv[7]);
        whhh[q] = int4{(int)b0, (int)b1, (int)b2, (int)b3};
        whhl[q] = int4{(int)cvt_pk(hv[0] - lo16f(b0), hv[1] - hi16f(b0)),
                       (int)cvt_pk(hv[2] - lo16f(b1), hv[3] - hi16f(b1)),
                       (int)cvt_pk(hv[4] - lo16f(b2), hv[5] - hi16f(b2)),
                       (int)cvt_pk(hv[6] - lo16f(b3), hv[7] - hi16f(b3))};
        biasr[q] = (bih[cell * 128 + g] + bhh[cell * 128 + g]) * SCALE;
    }

    // ---- staging map: thread -> (b = tid>>4, d0 = (tid&15)*2), 2 float2 loads ----
    const int sb = tid >> 4;
    const int d0 = (tid & 15) * 2;
    const float* xg0 = x + (size_t)(gb0 + sb) * TDC + (size_t)d0 * Cn + cellbase;
    const float* xcur = xg0 + DC;   // prefetch cursor (t+1)

    // ---- sp store map (gh==0 waves): lane -> (b_loc = lane&15, kg2 = lane>>4) ----
    const int b_loc = lane & 15, kg2 = lane >> 4;
    const int sm = cell >> 5, sn = cell & 31;
    const int ppx = (sm + 1) * MP + (sn + 1);
    unsigned short* spcur = sp + (((size_t)(gb0 + b_loc) * (Tn * 4) + kg2) * PPXN + ppx) * 8;

    float hD[4] = {}, cst[4] = {};
    float2 nx0 = *(const float2*)xg0;
    float2 nx1 = *(const float2*)(xg0 + Cn);

    for (int t = 0; t < Tn; ++t) {
        const int bufi = t & 1;
        // -- stage x(t): bf16 hi only, b32 writes --
#pragma unroll
        for (int cc = 0; cc < 2; ++cc) {
            float f0 = cc ? nx0.y : nx0.x;
            float f1 = cc ? nx1.y : nx1.x;
            *(unsigned*)&lds.Xh[bufi][cc][sb][d0] = cvt_pk(f0, f1);
        }
        // -- write h(t-1) -> Hf[bufi] (rows kg*4+r, col gh*16+l16) --
#pragma unroll
        for (int r = 0; r < 4; ++r)
            lds.Hf[bufi][ci][kg * 4 + r][gh * 16 + l16] = hD[r];
        // -- prefetch x(t+1) --
        if (t < Tn - 1) {
            nx0 = *(const float2*)xcur;
            nx1 = *(const float2*)(xcur + Cn);
            xcur += DC;
        }
        __syncthreads();

        // -- fragments (rows b = l16, k = kg*8..+7) --
        int4 xfh = *(const int4*)&lds.Xh[bufi][ci][l16][kg * 8];
        const float* hp = &lds.Hf[bufi][ci][l16][kg * 8];
        float4 ha = *(const float4*)hp;
        float4 hb = *(const float4*)(hp + 4);
        unsigned p0 = cvt_pk(ha.x, ha.y), p1 = cvt_pk(ha.z, ha.w);
        unsigned p2 = cvt_pk(hb.x, hb.y), p3 = cvt_pk(hb.z, hb.w);
        int4 hfh = int4{(int)p0, (int)p1, (int)p2, (int)p3};
        int4 hfl = int4{(int)cvt_pk(ha.x - lo16f(p0), ha.y - hi16f(p0)),
                        (int)cvt_pk(ha.z - lo16f(p1), ha.w - hi16f(p1)),
                        (int)cvt_pk(hb.x - lo16f(p2), hb.y - hi16f(p2)),
                        (int)cvt_pk(hb.z - lo16f(p3), hb.w - hi16f(p3))};

        // -- sp store h(t-1) bf16-hi (gh==0 waves; (b_loc,kg2) == (l16,kg) map) --
        if (gh == 0 && t > 0) {
            int4 sv = {(int)p0, (int)p1, (int)p2, (int)p3};
            *(int4*)spcur = sv;
            spcur += IMGS;
        }

        // -- MFMA: 4 q-tiles x 5-term (2-term x-path + 3-term h-path) --
        f32x4 acc[4];
#pragma unroll
        for (int q = 0; q < 4; ++q) {
            f32x4 a = {biasr[q], biasr[q], biasr[q], biasr[q]};
            a = __builtin_amdgcn_mfma_f32_16x16x32_bf16(bc(xfh), bc(wihh[q]), a, 0, 0, 0);
            a = __builtin_amdgcn_mfma_f32_16x16x32_bf16(bc(xfh), bc(wihl[q]), a, 0, 0, 0);
            a = __builtin_amdgcn_mfma_f32_16x16x32_bf16(bc(hfh), bc(whhh[q]), a, 0, 0, 0);
            a = __builtin_amdgcn_mfma_f32_16x16x32_bf16(bc(hfl), bc(whhh[q]), a, 0, 0, 0);
            a = __builtin_amdgcn_mfma_f32_16x16x32_bf16(bc(hfh), bc(whhl[q]), a, 0, 0, 0);
            acc[q] = a;
        }

        // -- gates (pre-scaled by log2e): rows b = kg*4+r, h col gh*16+l16 --
#pragma unroll
        for (int r = 0; r < 4; ++r) {
            float gi = acc[0][r], gf = acc[1][r];
            float gg = acc[2][r], go = acc[3][r];
            float ig = rcp_(1.f + exp2_(-gi));
            float fg = rcp_(1.f + exp2_(-gf));
            float gt = 1.f - 2.f * rcp_(1.f + exp2_(gg + gg));
            float og = rcp_(1.f + exp2_(-go));
            float c  = fg * cst[r] + ig * gt;
            cst[r] = c;
            float tc = 1.f - 2.f * rcp_(1.f + exp2_((2.f * SCALE) * c));
            hD[r] = og * tc;
        }
    }

    // ---- epilogue: flush h(Tn-1) ----
#pragma unroll
    for (int r = 0; r < 4; ++r)
        lds.Hf[0][ci][kg * 4 + r][gh * 16 + l16] = hD[r];
    __syncthreads();
    if (gh == 0) {
        const float* hq = &lds.Hf[0][ci][l16][kg * 8];
        float4 ea = *(const float4*)hq;
        float4 eb = *(const float4*)(hq + 4);
        int4 sv = {(int)cvt_pk(ea.x, ea.y), (int)cvt_pk(ea.z, ea.w),
                   (int)cvt_pk(eb.x, eb.y), (int)cvt_pk(eb.z, eb.w)};
        *(int4*)spcur = sv;
    }
}

// ---- conv: 768 blocks (b,t) x 512 thr, 2 px/thread, fp32 math, fused sigmoid ----
__global__ __launch_bounds__(512, 4)
void conv_k4(const unsigned short* __restrict__ sp,
             const float* __restrict__ cw,
             const float* __restrict__ cb,
             float* __restrict__ out)
{
    __shared__ float wlds[9][32];
    const int tid = threadIdx.x;
    const int img = blockIdx.x;
    if (tid < 288) wlds[tid >> 5][tid & 31] = cw[(tid & 31) * 9 + (tid >> 5)];
    __syncthreads();
    const float bias = cb[0];
    float acc[2] = {bias, bias};
    int ppx[2];
#pragma unroll
    for (int pk = 0; pk < 2; ++pk) {
        int px = tid + pk * 512;
        ppx[pk] = ((px >> 5) + 1) * MP + (px & 31) + 1;
    }
#pragma unroll
    for (int hc = 0; hc < 4; ++hc) {
        float4 wa[9], wb[9];
#pragma unroll
        for (int tap = 0; tap < 9; ++tap) {
            wa[tap] = *(const float4*)&wlds[tap][hc * 8];
            wb[tap] = *(const float4*)&wlds[tap][hc * 8 + 4];
        }
        const unsigned short* plane = sp + (size_t)(img * 4 + hc) * (PPXN * 8);
#pragma unroll
        for (int pk = 0; pk < 2; ++pk) {
            const unsigned short* base = plane + (size_t)ppx[pk] * 8;
            float a = acc[pk];
#pragma unroll
            for (int dm = -1; dm <= 1; ++dm)
#pragma unroll
                for (int dn = -1; dn <= 1; ++dn) {
                    const int tap = (dm + 1) * 3 + (dn + 1);
                    int4 v = *(const int4*)(base + (dm * MP + dn) * 8);
                    float4 w0 = wa[tap], w1 = wb[tap];
                    a = fmaf(lo16f((unsigned)v.x), w0.x, a);
                    a = fmaf(hi16f((unsigned)v.x), w0.y, a);
                    a = fmaf(lo16f((unsigned)v.y), w0.z, a);
                    a = fmaf(hi16f((unsigned)v.y), w0.w, a);
                    a = fmaf(lo16f((unsigned)v.z), w1.x, a);
                    a = fmaf(hi16f((unsigned)v.z), w1.y, a);
                    a = fmaf(lo16f((unsigned)v.w), w1.z, a);
                    a = fmaf(hi16f((unsigned)v.w), w1.w, a);
                }
            acc[pk] = a;
        }
    }
#pragma unroll
    for (int pk = 0; pk < 2; ++pk)
        out[(size_t)img * 1024 + tid + pk * 512] = rcp_(1.f + exp2_(-SCALE * acc[pk]));
}

extern "C" void kernel_launch(void* const* d_in, const int* in_sizes, int n_in,
                              void* d_out, int out_size, void* d_ws, size_t ws_size,
                              hipStream_t stream) {
    const float* x   = (const float*)d_in[0];
    const float* Wih = (const float*)d_in[1];
    const float* Whh = (const float*)d_in[2];
    const float* bih = (const float*)d_in[3];
    const float* bhh = (const float*)d_in[4];
    const float* cw  = (const float*)d_in[5];
    const float* cb  = (const float*)d_in[6];
    float* out = (float*)d_out;
    unsigned short* sp = (unsigned short*)d_ws;  // bf16 (B,T, chunk4, 34,34, 8ch)

    zero_halo<<<792, 512, 0, stream>>>(sp);
    lstm_k14<<<1024, 256, 0, stream>>>(x, Wih, Whh, bih, bhh, sp);
    conv_k4<<<Bn * Tn, 512, 0, stream>>>(sp, cw, cb, out);
}

// Round 15
// 102.379 us; speedup vs baseline: 1.1927x; 1.0887x over previous
//
#include <hip/hip_runtime.h>

#define Bn 32
#define Tn 24
#define Dn 32
#define Hn 32
#define Cn 1024
#define DC (Dn*Cn)      /* 32768 */
#define TDC (Tn*Dn*Cn)  /* 786432 */
#define MP 34
#define PPXN (MP*MP)    /* 1156 */
#define IMGS (MP*MP*32) /* shorts per image (4 planes * 1156 * 8) */
#define SCALE 1.442695041f

typedef __attribute__((ext_vector_type(8))) short bf16x8;
typedef __attribute__((ext_vector_type(4))) float f32x4;

__device__ __forceinline__ unsigned cvt_pk(float lo, float hi) {
    unsigned r; asm("v_cvt_pk_bf16_f32 %0, %1, %2" : "=v"(r) : "v"(lo), "v"(hi)); return r;
}
__device__ __forceinline__ float lo16f(unsigned u) { return __builtin_bit_cast(float, u << 16); }
__device__ __forceinline__ float hi16f(unsigned u) { return __builtin_bit_cast(float, u & 0xffff0000u); }
__device__ __forceinline__ float rcp_(float x) { return __builtin_amdgcn_rcpf(x); }
__device__ __forceinline__ float exp2_(float x) { return __builtin_amdgcn_exp2f(x); }
__device__ __forceinline__ bf16x8 bc(int4 v) { return __builtin_bit_cast(bf16x8, v); }

// LDS-only barrier: no vmcnt drain (x-prefetch loads & sp stores stay in flight).
__device__ __forceinline__ void lds_barrier() {
    asm volatile("s_waitcnt lgkmcnt(0)\n\ts_barrier" ::: "memory");
}

struct __align__(16) LdsT {
    unsigned short Xh[2][2][32][48];  // [buf][cell][b][d pad48] bf16(x)
    float Hf[2][2][32][36];           // [buf][cell][b][hid pad36] fp32 h
};  // 30720 B

// ---- zero the 1-px halo ring of every (img, chunk) plane ----
__global__ __launch_bounds__(512)
void zero_halo(unsigned short* __restrict__ sp) {
    int gid = blockIdx.x * 512 + threadIdx.x;
    if (gid >= 3072 * 132) return;
    int plane = gid / 132;
    int r = gid - plane * 132;
    int m, n;
    if (r < 34)       { m = 0;      n = r; }
    else if (r < 68)  { m = 33;     n = r - 34; }
    else if (r < 100) { m = r - 67; n = 0; }
    else              { m = r - 99; n = 33; }
    int4 z = {0, 0, 0, 0};
    *(int4*)(sp + ((size_t)plane * PPXN + m * MP + n) * 8) = z;
}

// ---- LSTM: grid 512 x 256 thr. Block = 2 cells x 32 batch (k10 structure).
// wave w: cell ci = w>>1, gate-half half = w&1; 2 mt-tiles sequential (fat waves).
// 5-term MFMA (x bf16-hi only), split x/h accumulators, raw LDS barrier,
// pointer cursors. waves_per_eu(3,3) = the proven spill-free allocation.
__global__ __launch_bounds__(256) __attribute__((amdgpu_waves_per_eu(3, 3)))
void lstm_k15(const float* __restrict__ x,
              const float* __restrict__ Wih,
              const float* __restrict__ Whh,
              const float* __restrict__ bih,
              const float* __restrict__ bhh,
              unsigned short* __restrict__ sp)
{
    __shared__ LdsT lds;
    const int tid  = threadIdx.x;
    const int lane = tid & 63;
    const int wave = tid >> 6;
    const int ci   = wave >> 1;
    const int half = wave & 1;
    const int l16  = lane & 15;
    const int kg   = lane >> 4;
    const int bid  = blockIdx.x;
    const int cellbase = (bid & 7) * 128 + (bid >> 3) * 2;  // XCD-contiguous cells
    const int cell = cellbase + ci;

    // ---- W fragments (int4), split hi/lo via cvt_pk, pre-scaled by log2e ----
    int4 wihh[4], wihl[4], whhh[4], whhl[4];
    float biasr[4];
#pragma unroll
    for (int q = 0; q < 4; ++q) {
        const int g = q * 32 + half * 16 + l16;
        const float* wp = Wih + (size_t)cell * 4096 + g * 32 + kg * 8;
        const float* hp = Whh + (size_t)cell * 4096 + g * 32 + kg * 8;
        float wv[8], hv[8];
#pragma unroll
        for (int j = 0; j < 8; ++j) { wv[j] = wp[j] * SCALE; hv[j] = hp[j] * SCALE; }
        unsigned a0 = cvt_pk(wv[0], wv[1]), a1 = cvt_pk(wv[2], wv[3]);
        unsigned a2 = cvt_pk(wv[4], wv[5]), a3 = cvt_pk(wv[6], wv[7]);
        wihh[q] = int4{(int)a0, (int)a1, (int)a2, (int)a3};
        wihl[q] = int4{(int)cvt_pk(wv[0] - lo16f(a0), wv[1] - hi16f(a0)),
                       (int)cvt_pk(wv[2] - lo16f(a1), wv[3] - hi16f(a1)),
                       (int)cvt_pk(wv[4] - lo16f(a2), wv[5] - hi16f(a2)),
                       (int)cvt_pk(wv[6] - lo16f(a3), wv[7] - hi16f(a3))};
        unsigned b0 = cvt_pk(hv[0], hv[1]), b1 = cvt_pk(hv[2], hv[3]);
        unsigned b2 = cvt_pk(hv[4], hv[5]), b3 = cvt_pk(hv[6], hv[7]);
        whhh[q] = int4{(int)b0, (int)b1, (int)b2, (int)b3};
        whhl[q] = int4{(int)cvt_pk(hv[0] - lo16f(b0), hv[1] - hi16f(b0)),
                       (int)cvt_pk(hv[2] - lo16f(b1), hv[3] - hi16f(b1)),
                       (int)cvt_pk(hv[4] - lo16f(b2), hv[5] - hi16f(b2)),
                       (int)cvt_pk(hv[6] - lo16f(b3), hv[7] - hi16f(b3))};
        biasr[q] = (bih[cell * 128 + g] + bhh[cell * 128 + g]) * SCALE;
    }

    // ---- staging map: thread -> (b = tid>>3, d0 = (tid&7)*4), float2 x 4 d's ----
    const int sb = tid >> 3;
    const int d0 = (tid & 7) * 4;
    const float* xg0 = x + (size_t)sb * TDC + (size_t)d0 * Cn + cellbase;
    const float* xcur = xg0 + DC;

    // sp store base (rows b = half*16 + l16, chunk kg)
    const int sm = cell >> 5, sn = cell & 31;
    const int ppx = (sm + 1) * MP + (sn + 1);
    unsigned short* spcur = sp + ((size_t)(half * 16 + l16) * Tn * 4 + kg) * (PPXN * 8)
                               + (size_t)ppx * 8;

    float hD[8] = {};   // h(t-1) D-layout: rows mt*16 + kg*4 + r
    float cst[8] = {};
    float2 nx[4];
#pragma unroll
    for (int k = 0; k < 4; ++k) nx[k] = *(const float2*)(xg0 + k * Cn);

    for (int t = 0; t < Tn; ++t) {
        const int bufi = t & 1;
        // -- stage x(t): bf16-hi only, int2 writes --
#pragma unroll
        for (int cc = 0; cc < 2; ++cc) {
            float f0 = cc ? nx[0].y : nx[0].x;
            float f1 = cc ? nx[1].y : nx[1].x;
            float f2 = cc ? nx[2].y : nx[2].x;
            float f3 = cc ? nx[3].y : nx[3].x;
            int2 hi2 = {(int)cvt_pk(f0, f1), (int)cvt_pk(f2, f3)};
            *(int2*)&lds.Xh[bufi][cc][sb][d0] = hi2;
        }
        // -- write h(t-1) -> Hf[bufi] --
#pragma unroll
        for (int i = 0; i < 8; ++i) {
            int mt = i >> 2, r = i & 3;
            lds.Hf[bufi][ci][mt * 16 + kg * 4 + r][half * 16 + l16] = hD[i];
        }
        // -- prefetch x(t+1): stays in flight across the raw barrier --
        if (t < Tn - 1) {
#pragma unroll
            for (int k = 0; k < 4; ++k)
                nx[k] = *(const float2*)(xcur + k * Cn);
            xcur += DC;
        }
        lds_barrier();

        unsigned sphi0 = 0, sphi1 = 0, sphi2 = 0, sphi3 = 0;
        // -- mt tiles sequential (fat wave: 2 tiles, 16 indep MFMA chains) --
#pragma unroll
        for (int mt = 0; mt < 2; ++mt) {
            int4 xfh = *(const int4*)&lds.Xh[bufi][ci][mt * 16 + l16][kg * 8];
            const float* hp = &lds.Hf[bufi][ci][mt * 16 + l16][kg * 8];
            float4 ha = *(const float4*)hp;
            float4 hb = *(const float4*)(hp + 4);
            unsigned p0 = cvt_pk(ha.x, ha.y), p1 = cvt_pk(ha.z, ha.w);
            unsigned p2 = cvt_pk(hb.x, hb.y), p3 = cvt_pk(hb.z, hb.w);
            int4 hfh = int4{(int)p0, (int)p1, (int)p2, (int)p3};
            int4 hfl = int4{(int)cvt_pk(ha.x - lo16f(p0), ha.y - hi16f(p0)),
                            (int)cvt_pk(ha.z - lo16f(p1), ha.w - hi16f(p1)),
                            (int)cvt_pk(hb.x - lo16f(p2), hb.y - hi16f(p2)),
                            (int)cvt_pk(hb.z - lo16f(p3), hb.w - hi16f(p3))};
            if (mt == half) { sphi0 = p0; sphi1 = p1; sphi2 = p2; sphi3 = p3; }

            // split accumulators: x-path (2-deep) and h-path (3-deep), independent
            f32x4 acc[4];
#pragma unroll
            for (int q = 0; q < 4; ++q) {
                f32x4 ax = {biasr[q], biasr[q], biasr[q], biasr[q]};
                ax = __builtin_amdgcn_mfma_f32_16x16x32_bf16(bc(xfh), bc(wihh[q]), ax, 0, 0, 0);
                ax = __builtin_amdgcn_mfma_f32_16x16x32_bf16(bc(xfh), bc(wihl[q]), ax, 0, 0, 0);
                f32x4 ah = {0.f, 0.f, 0.f, 0.f};
                ah = __builtin_amdgcn_mfma_f32_16x16x32_bf16(bc(hfh), bc(whhh[q]), ah, 0, 0, 0);
                ah = __builtin_amdgcn_mfma_f32_16x16x32_bf16(bc(hfl), bc(whhh[q]), ah, 0, 0, 0);
                ah = __builtin_amdgcn_mfma_f32_16x16x32_bf16(bc(hfh), bc(whhl[q]), ah, 0, 0, 0);
                acc[q] = ax + ah;
            }
            // gates for this mt tile
#pragma unroll
            for (int r = 0; r < 4; ++r) {
                float gi = acc[0][r], gf = acc[1][r];
                float gg = acc[2][r], go = acc[3][r];
                float ig = rcp_(1.f + exp2_(-gi));
                float fg = rcp_(1.f + exp2_(-gf));
                float gt = 1.f - 2.f * rcp_(1.f + exp2_(gg + gg));
                float og = rcp_(1.f + exp2_(-go));
                float c  = fg * cst[mt * 4 + r] + ig * gt;
                cst[mt * 4 + r] = c;
                float tc = 1.f - 2.f * rcp_(1.f + exp2_((2.f * SCALE) * c));
                hD[mt * 4 + r] = og * tc;
            }
        }

        // -- store h(t-1) bf16-hi to sp --
        if (t > 0) {
            int4 sv = {(int)sphi0, (int)sphi1, (int)sphi2, (int)sphi3};
            *(int4*)spcur = sv;
            spcur += IMGS;
        }
    }

    // ---- epilogue: flush h(Tn-1) ----
#pragma unroll
    for (int i = 0; i < 8; ++i) {
        int mt = i >> 2, r = i & 3;
        lds.Hf[0][ci][mt * 16 + kg * 4 + r][half * 16 + l16] = hD[i];
    }
    lds_barrier();
    {
        const float* hp = &lds.Hf[0][ci][half * 16 + l16][kg * 8];
        float4 ha = *(const float4*)hp;
        float4 hb = *(const float4*)(hp + 4);
        int4 sv = {(int)cvt_pk(ha.x, ha.y), (int)cvt_pk(ha.z, ha.w),
                   (int)cvt_pk(hb.x, hb.y), (int)cvt_pk(hb.z, hb.w)};
        *(int4*)spcur = sv;
    }
}

// ---- conv: 768 blocks (b,t) x 512 thr, 2 px/thread, fp32 math, fused sigmoid ----
__global__ __launch_bounds__(512, 4)
void conv_k4(const unsigned short* __restrict__ sp,
             const float* __restrict__ cw,
             const float* __restrict__ cb,
             float* __restrict__ out)
{
    __shared__ float wlds[9][32];
    const int tid = threadIdx.x;
    const int img = blockIdx.x;
    if (tid < 288) wlds[tid >> 5][tid & 31] = cw[(tid & 31) * 9 + (tid >> 5)];
    __syncthreads();
    const float bias = cb[0];
    float acc[2] = {bias, bias};
    int ppx[2];
#pragma unroll
    for (int pk = 0; pk < 2; ++pk) {
        int px = tid + pk * 512;
        ppx[pk] = ((px >> 5) + 1) * MP + (px & 31) + 1;
    }
#pragma unroll
    for (int hc = 0; hc < 4; ++hc) {
        float4 wa[9], wb[9];
#pragma unroll
        for (int tap = 0; tap < 9; ++tap) {
            wa[tap] = *(const float4*)&wlds[tap][hc * 8];
            wb[tap] = *(const float4*)&wlds[tap][hc * 8 + 4];
        }
        const unsigned short* plane = sp + (size_t)(img * 4 + hc) * (PPXN * 8);
#pragma unroll
        for (int pk = 0; pk < 2; ++pk) {
            const unsigned short* base = plane + (size_t)ppx[pk] * 8;
            float a = acc[pk];
#pragma unroll
            for (int dm = -1; dm <= 1; ++dm)
#pragma unroll
                for (int dn = -1; dn <= 1; ++dn) {
                    const int tap = (dm + 1) * 3 + (dn + 1);
                    int4 v = *(const int4*)(base + (dm * MP + dn) * 8);
                    float4 w0 = wa[tap], w1 = wb[tap];
                    a = fmaf(lo16f((unsigned)v.x), w0.x, a);
                    a = fmaf(hi16f((unsigned)v.x), w0.y, a);
                    a = fmaf(lo16f((unsigned)v.y), w0.z, a);
                    a = fmaf(hi16f((unsigned)v.y), w0.w, a);
                    a = fmaf(lo16f((unsigned)v.z), w1.x, a);
                    a = fmaf(hi16f((unsigned)v.z), w1.y, a);
                    a = fmaf(lo16f((unsigned)v.w), w1.z, a);
                    a = fmaf(hi16f((unsigned)v.w), w1.w, a);
                }
            acc[pk] = a;
        }
    }
#pragma unroll
    for (int pk = 0; pk < 2; ++pk)
        out[(size_t)img * 1024 + tid + pk * 512] = rcp_(1.f + exp2_(-SCALE * acc[pk]));
}

extern "C" void kernel_launch(void* const* d_in, const int* in_sizes, int n_in,
                              void* d_out, int out_size, void* d_ws, size_t ws_size,
                              hipStream_t stream) {
    const float* x   = (const float*)d_in[0];
    const float* Wih = (const float*)d_in[1];
    const float* Whh = (const float*)d_in[2];
    const float* bih = (const float*)d_in[3];
    const float* bhh = (const float*)d_in[4];
    const float* cw  = (const float*)d_in[5];
    const float* cb  = (const float*)d_in[6];
    float* out = (float*)d_out;
    unsigned short* sp = (unsigned short*)d_ws;  // bf16 (B,T, chunk4, 34,34, 8ch)

    zero_halo<<<792, 512, 0, stream>>>(sp);
    lstm_k15<<<512, 256, 0, stream>>>(x, Wih, Whh, bih, bhh, sp);
    conv_k4<<<Bn * Tn, 512, 0, stream>>>(sp, cw, cb, out);
}

// Round 16
// 100.401 us; speedup vs baseline: 1.2162x; 1.0197x over previous
//
#include <hip/hip_runtime.h>

#define Bn 32
#define Tn 24
#define Dn 32
#define Hn 32
#define Cn 1024
#define DC (Dn*Cn)      /* 32768 */
#define TDC (Tn*Dn*Cn)  /* 786432 */
#define MP 34
#define PPXN (MP*MP)    /* 1156 */
#define IMGS (MP*MP*32) /* shorts per image (4 planes * 1156 * 8) */
#define SCALE 1.442695041f

typedef __attribute__((ext_vector_type(8))) short bf16x8;
typedef __attribute__((ext_vector_type(4))) float f32x4;

__device__ __forceinline__ unsigned cvt_pk(float lo, float hi) {
    unsigned r; asm("v_cvt_pk_bf16_f32 %0, %1, %2" : "=v"(r) : "v"(lo), "v"(hi)); return r;
}
__device__ __forceinline__ float lo16f(unsigned u) { return __builtin_bit_cast(float, u << 16); }
__device__ __forceinline__ float hi16f(unsigned u) { return __builtin_bit_cast(float, u & 0xffff0000u); }
__device__ __forceinline__ float rcp_(float x) { return __builtin_amdgcn_rcpf(x); }
__device__ __forceinline__ float exp2_(float x) { return __builtin_amdgcn_exp2f(x); }
__device__ __forceinline__ bf16x8 bc(int4 v) { return __builtin_bit_cast(bf16x8, v); }

// LDS-only barrier: no vmcnt drain (x-prefetch loads & sp stores stay in flight).
__device__ __forceinline__ void lds_barrier() {
    asm volatile("s_waitcnt lgkmcnt(0)\n\ts_barrier" ::: "memory");
}

struct __align__(16) LdsT {
    unsigned short Xh[2][4][16][48];  // [buf][cell][b][d pad48] bf16(x) hi
    float Hf[2][4][16][36];           // [buf][cell][b][hid pad36] fp32 h
};  // 12288 + 18432 = 30720 B -> 2 blocks/CU

// ---- zero the 1-px halo ring of every (img, chunk) plane ----
__global__ __launch_bounds__(512)
void zero_halo(unsigned short* __restrict__ sp) {
    int gid = blockIdx.x * 512 + threadIdx.x;
    if (gid >= 3072 * 132) return;
    int plane = gid / 132;
    int r = gid - plane * 132;
    int m, n;
    if (r < 34)       { m = 0;      n = r; }
    else if (r < 68)  { m = 33;     n = r - 34; }
    else if (r < 100) { m = r - 67; n = 0; }
    else              { m = r - 99; n = 33; }
    int4 z = {0, 0, 0, 0};
    *(int4*)(sp + ((size_t)plane * PPXN + m * MP + n) * 8) = z;
}

// ---- LSTM: grid 512 = 256 cellgroups(4 cells) x 2 bslices; 512 thr = 8 waves.
// wave w: cell ci = w>>1, gate-half gh = w&1 (M=16, N=64, W=64 u32 -> no spill).
// KEY: x loaded as ONE dense float4/thread/step (16B = 4 cells) -> 2x fewer
// distinct-line touches + 4x fewer load instrs than the 2-cell float2 gather.
__global__ __launch_bounds__(512, 2)
void lstm_k16(const float* __restrict__ x,
              const float* __restrict__ Wih,
              const float* __restrict__ Whh,
              const float* __restrict__ bih,
              const float* __restrict__ bhh,
              unsigned short* __restrict__ sp)
{
    __shared__ LdsT lds;
    const int tid  = threadIdx.x;
    const int lane = tid & 63;
    const int wave = tid >> 6;
    const int ci   = wave >> 1;
    const int gh   = wave & 1;
    const int l16  = lane & 15;
    const int kg   = lane >> 4;
    const int bid  = blockIdx.x;
    const int xcd  = bid & 7, v = bid >> 3;        // v 0..63
    const int cg   = xcd * 32 + (v & 31);           // 0..255, XCD-contiguous groups
    const int bs   = v >> 5;                        // 0..1
    const int cellbase = cg * 4;
    const int cell = cellbase + ci;
    const int gb0  = bs * 16;

    // ---- W fragments (int4), split hi/lo via cvt_pk, pre-scaled by log2e ----
    int4 wihh[4], wihl[4], whhh[4], whhl[4];
    float biasr[4];
#pragma unroll
    for (int q = 0; q < 4; ++q) {
        const int g = q * 32 + gh * 16 + l16;
        const float* wp = Wih + (size_t)cell * 4096 + g * 32 + kg * 8;
        const float* hp = Whh + (size_t)cell * 4096 + g * 32 + kg * 8;
        float wv[8], hv[8];
#pragma unroll
        for (int j = 0; j < 8; ++j) { wv[j] = wp[j] * SCALE; hv[j] = hp[j] * SCALE; }
        unsigned a0 = cvt_pk(wv[0], wv[1]), a1 = cvt_pk(wv[2], wv[3]);
        unsigned a2 = cvt_pk(wv[4], wv[5]), a3 = cvt_pk(wv[6], wv[7]);
        wihh[q] = int4{(int)a0, (int)a1, (int)a2, (int)a3};
        wihl[q] = int4{(int)cvt_pk(wv[0] - lo16f(a0), wv[1] - hi16f(a0)),
                       (int)cvt_pk(wv[2] - lo16f(a1), wv[3] - hi16f(a1)),
                       (int)cvt_pk(wv[4] - lo16f(a2), wv[5] - hi16f(a2)),
                       (int)cvt_pk(wv[6] - lo16f(a3), wv[7] - hi16f(a3))};
        unsigned b0 = cvt_pk(hv[0], hv[1]), b1 = cvt_pk(hv[2], hv[3]);
        unsigned b2 = cvt_pk(hv[4], hv[5]), b3 = cvt_pk(hv[6], hv[7]);
        whhh[q] = int4{(int)b0, (int)b1, (int)b2, (int)b3};
        whhl[q] = int4{(int)cvt_pk(hv[0] - lo16f(b0), hv[1] - hi16f(b0)),
                       (int)cvt_pk(hv[2] - lo16f(b1), hv[3] - hi16f(b1)),
                       (int)cvt_pk(hv[4] - lo16f(b2), hv[5] - hi16f(b2)),
                       (int)cvt_pk(hv[6] - lo16f(b3), hv[7] - hi16f(b3))};
        biasr[q] = (bih[cell * 128 + g] + bhh[cell * 128 + g]) * SCALE;
    }

    // ---- x staging: thread -> (b = tid>>5, d = tid&31); float4 = 4 cells ----
    const int sb = tid >> 5;
    const int sd = tid & 31;
    const float* xg0 = x + (size_t)(gb0 + sb) * TDC + (size_t)sd * Cn + cellbase;
    const float* xcur = xg0 + DC;

    // ---- sp store map (gh==0 waves): lane -> (b_loc = lane&15, kg2 = lane>>4) ----
    const int b_loc = lane & 15, kg2 = lane >> 4;
    const int sm = cell >> 5, sn = cell & 31;
    const int ppx = (sm + 1) * MP + (sn + 1);
    unsigned short* spcur = sp + (((size_t)(gb0 + b_loc) * (Tn * 4) + kg2) * PPXN + ppx) * 8;

    float hD[4] = {}, cst[4] = {};
    float4 gx = *(const float4*)xg0;

    for (int t = 0; t < Tn; ++t) {
        const int bufi = t & 1;
        // -- stage x(t): 4 cells bf16-hi, 4 b16 stores --
        {
            unsigned u01 = cvt_pk(gx.x, gx.y), u23 = cvt_pk(gx.z, gx.w);
            lds.Xh[bufi][0][sb][sd] = (unsigned short)u01;
            lds.Xh[bufi][1][sb][sd] = (unsigned short)(u01 >> 16);
            lds.Xh[bufi][2][sb][sd] = (unsigned short)u23;
            lds.Xh[bufi][3][sb][sd] = (unsigned short)(u23 >> 16);
        }
        // -- write h(t-1) -> Hf[bufi] (rows kg*4+r, col gh*16+l16) --
#pragma unroll
        for (int r = 0; r < 4; ++r)
            lds.Hf[bufi][ci][kg * 4 + r][gh * 16 + l16] = hD[r];
        // -- prefetch x(t+1): one dense float4; stays in flight across barrier --
        if (t < Tn - 1) {
            gx = *(const float4*)xcur;
            xcur += DC;
        }
        lds_barrier();

        // -- fragments (rows b = l16, k = kg*8..+7) --
        int4 xfh = *(const int4*)&lds.Xh[bufi][ci][l16][kg * 8];
        const float* hp = &lds.Hf[bufi][ci][l16][kg * 8];
        float4 ha = *(const float4*)hp;
        float4 hb = *(const float4*)(hp + 4);
        unsigned p0 = cvt_pk(ha.x, ha.y), p1 = cvt_pk(ha.z, ha.w);
        unsigned p2 = cvt_pk(hb.x, hb.y), p3 = cvt_pk(hb.z, hb.w);
        int4 hfh = int4{(int)p0, (int)p1, (int)p2, (int)p3};
        int4 hfl = int4{(int)cvt_pk(ha.x - lo16f(p0), ha.y - hi16f(p0)),
                        (int)cvt_pk(ha.z - lo16f(p1), ha.w - hi16f(p1)),
                        (int)cvt_pk(hb.x - lo16f(p2), hb.y - hi16f(p2)),
                        (int)cvt_pk(hb.z - lo16f(p3), hb.w - hi16f(p3))};

        // -- sp store h(t-1) bf16-hi (gh==0 waves; (b_loc,kg2)==(l16,kg) map) --
        if (gh == 0 && t > 0) {
            int4 sv = {(int)p0, (int)p1, (int)p2, (int)p3};
            *(int4*)spcur = sv;
            spcur += IMGS;
        }

        // -- MFMA: 4 q-tiles x 5-term --
        f32x4 acc[4];
#pragma unroll
        for (int q = 0; q < 4; ++q) {
            f32x4 a = {biasr[q], biasr[q], biasr[q], biasr[q]};
            a = __builtin_amdgcn_mfma_f32_16x16x32_bf16(bc(xfh), bc(wihh[q]), a, 0, 0, 0);
            a = __builtin_amdgcn_mfma_f32_16x16x32_bf16(bc(xfh), bc(wihl[q]), a, 0, 0, 0);
            a = __builtin_amdgcn_mfma_f32_16x16x32_bf16(bc(hfh), bc(whhh[q]), a, 0, 0, 0);
            a = __builtin_amdgcn_mfma_f32_16x16x32_bf16(bc(hfl), bc(whhh[q]), a, 0, 0, 0);
            a = __builtin_amdgcn_mfma_f32_16x16x32_bf16(bc(hfh), bc(whhl[q]), a, 0, 0, 0);
            acc[q] = a;
        }

        // -- gates (pre-scaled by log2e): rows b = kg*4+r, h col gh*16+l16 --
#pragma unroll
        for (int r = 0; r < 4; ++r) {
            float gi = acc[0][r], gf = acc[1][r];
            float gg = acc[2][r], go = acc[3][r];
            float ig = rcp_(1.f + exp2_(-gi));
            float fg = rcp_(1.f + exp2_(-gf));
            float gt = 1.f - 2.f * rcp_(1.f + exp2_(gg + gg));
            float og = rcp_(1.f + exp2_(-go));
            float c  = fg * cst[r] + ig * gt;
            cst[r] = c;
            float tc = 1.f - 2.f * rcp_(1.f + exp2_((2.f * SCALE) * c));
            hD[r] = og * tc;
        }
    }

    // ---- epilogue: flush h(Tn-1) ----
#pragma unroll
    for (int r = 0; r < 4; ++r)
        lds.Hf[0][ci][kg * 4 + r][gh * 16 + l16] = hD[r];
    lds_barrier();
    if (gh == 0) {
        const float* hq = &lds.Hf[0][ci][l16][kg * 8];
        float4 ea = *(const float4*)hq;
        float4 eb = *(const float4*)(hq + 4);
        int4 sv = {(int)cvt_pk(ea.x, ea.y), (int)cvt_pk(ea.z, ea.w),
                   (int)cvt_pk(eb.x, eb.y), (int)cvt_pk(eb.z, eb.w)};
        *(int4*)spcur = sv;
    }
}

// ---- conv: 768 blocks (b,t) x 512 thr, 2 px/thread, fp32 math, fused sigmoid ----
__global__ __launch_bounds__(512, 4)
void conv_k4(const unsigned short* __restrict__ sp,
             const float* __restrict__ cw,
             const float* __restrict__ cb,
             float* __restrict__ out)
{
    __shared__ float wlds[9][32];
    const int tid = threadIdx.x;
    const int img = blockIdx.x;
    if (tid < 288) wlds[tid >> 5][tid & 31] = cw[(tid & 31) * 9 + (tid >> 5)];
    __syncthreads();
    const float bias = cb[0];
    float acc[2] = {bias, bias};
    int ppx[2];
#pragma unroll
    for (int pk = 0; pk < 2; ++pk) {
        int px = tid + pk * 512;
        ppx[pk] = ((px >> 5) + 1) * MP + (px & 31) + 1;
    }
#pragma unroll
    for (int hc = 0; hc < 4; ++hc) {
        float4 wa[9], wb[9];
#pragma unroll
        for (int tap = 0; tap < 9; ++tap) {
            wa[tap] = *(const float4*)&wlds[tap][hc * 8];
            wb[tap] = *(const float4*)&wlds[tap][hc * 8 + 4];
        }
        const unsigned short* plane = sp + (size_t)(img * 4 + hc) * (PPXN * 8);
#pragma unroll
        for (int pk = 0; pk < 2; ++pk) {
            const unsigned short* base = plane + (size_t)ppx[pk] * 8;
            float a = acc[pk];
#pragma unroll
            for (int dm = -1; dm <= 1; ++dm)
#pragma unroll
                for (int dn = -1; dn <= 1; ++dn) {
                    const int tap = (dm + 1) * 3 + (dn + 1);
                    int4 v = *(const int4*)(base + (dm * MP + dn) * 8);
                    float4 w0 = wa[tap], w1 = wb[tap];
                    a = fmaf(lo16f((unsigned)v.x), w0.x, a);
                    a = fmaf(hi16f((unsigned)v.x), w0.y, a);
                    a = fmaf(lo16f((unsigned)v.y), w0.z, a);
                    a = fmaf(hi16f((unsigned)v.y), w0.w, a);
                    a = fmaf(lo16f((unsigned)v.z), w1.x, a);
                    a = fmaf(hi16f((unsigned)v.z), w1.y, a);
                    a = fmaf(lo16f((unsigned)v.w), w1.z, a);
                    a = fmaf(hi16f((unsigned)v.w), w1.w, a);
                }
            acc[pk] = a;
        }
    }
#pragma unroll
    for (int pk = 0; pk < 2; ++pk)
        out[(size_t)img * 1024 + tid + pk * 512] = rcp_(1.f + exp2_(-SCALE * acc[pk]));
}

extern "C" void kernel_launch(void* const* d_in, const int* in_sizes, int n_in,
                              void* d_out, int out_size, void* d_ws, size_t ws_size,
                              hipStream_t stream) {
    const float* x   = (const float*)d_in[0];
    const float* Wih = (const float*)d_in[1];
    const float* Whh = (const float*)d_in[2];
    const float* bih = (const float*)d_in[3];
    const float* bhh = (const float*)d_in[4];
    const float* cw  = (const float*)d_in[5];
    const float* cb  = (const float*)d_in[6];
    float* out = (float*)d_out;
    unsigned short* sp = (unsigned short*)d_ws;  // bf16 (B,T, chunk4, 34,34, 8ch)

    zero_halo<<<792, 512, 0, stream>>>(sp);
    lstm_k16<<<512, 512, 0, stream>>>(x, Wih, Whh, bih, bhh, sp);
    conv_k4<<<Bn * Tn, 512, 0, stream>>>(sp, cw, cb, out);
}